// Round 1
// baseline (364.024 us; speedup 1.0000x reference)
//
#include <hip/hip_runtime.h>
#include <hip/hip_bf16.h>

#define B_ 4096
#define L_ 128
#define D_ 100
#define S_ 1024
#define R_ 512
#define K1_ 1224   // 2*D + S
#define N1_ 1024   // 2*R
#define EPS_ 1e-5f

// ---------------- K1: ragged mean-pool + build qas = [pooled(200) | statement(1024)] ----
__global__ __launch_bounds__(256) void pool_kernel(
    const float* __restrict__ sv, const int* __restrict__ qa_ids,
    const int* __restrict__ qa_lens, const float* __restrict__ emb,
    float* __restrict__ qas) {
  int b = blockIdx.x;
  int t = threadIdx.x;                 // 256 threads
  __shared__ int ids[L_ * 2];          // 256 ints
  int len = qa_lens[b];
  ids[t] = qa_ids[(size_t)b * (L_ * 2) + t];
  __syncthreads();
  if (t < 200) {
    int k = t / 100, d = t % 100;
    float acc = 0.f;
    for (int l = 0; l < len; ++l) {
      int id = ids[l * 2 + k];
      acc += emb[(size_t)id * D_ + d];
    }
    float denom = (float)(len > 0 ? len : 1);
    qas[(size_t)b * K1_ + t] = acc / denom;
  }
  for (int i = t; i < S_; i += 256)
    qas[(size_t)b * K1_ + 200 + i] = sv[(size_t)b * S_ + i];
}

// ---------------- tiled f32 GEMM: C[M,N] = A[M,K] @ B[K,N] + bias (+ReLU) --------------
template <bool RELU>
__global__ __launch_bounds__(256) void gemm_kernel(
    const float* __restrict__ A, const float* __restrict__ Bm,
    const float* __restrict__ bias, float* __restrict__ C,
    int M, int K, int N) {
  const int bx = blockIdx.x, by = blockIdx.y;
  const int t = threadIdx.x;
  const int tx = t & 15, ty = t >> 4;
  __shared__ float As[8][64];
  __shared__ float Bs[8][64];
  float acc[4][4] = {};
  const int row0 = by * 64, col0 = bx * 64;
  for (int k0 = 0; k0 < K; k0 += 8) {
    {  // A tile: 64 rows x 8 k, thread t -> row t/4, k (t%4)*2 + {0,1}
      int m = t >> 2;
      int kk = (t & 3) * 2;
      const float* ap = A + (size_t)(row0 + m) * K + k0 + kk;
      float2 v = *reinterpret_cast<const float2*>(ap);
      As[kk][m] = v.x;
      As[kk + 1][m] = v.y;
    }
    {  // B tile: 8 k x 64 cols, thread t -> k t/64 + {0,4}, col t%64
      int kk = t >> 6;
      int c = t & 63;
      Bs[kk][c]     = Bm[(size_t)(k0 + kk) * N + col0 + c];
      Bs[kk + 4][c] = Bm[(size_t)(k0 + kk + 4) * N + col0 + c];
    }
    __syncthreads();
#pragma unroll
    for (int kk = 0; kk < 8; ++kk) {
      float a[4], bb[4];
#pragma unroll
      for (int i = 0; i < 4; ++i) a[i] = As[kk][ty * 4 + i];
#pragma unroll
      for (int j = 0; j < 4; ++j) bb[j] = Bs[kk][tx * 4 + j];
#pragma unroll
      for (int i = 0; i < 4; ++i)
#pragma unroll
        for (int j = 0; j < 4; ++j) acc[i][j] += a[i] * bb[j];
    }
    __syncthreads();
  }
#pragma unroll
  for (int i = 0; i < 4; ++i) {
    int r = row0 + ty * 4 + i;
#pragma unroll
    for (int j = 0; j < 4; ++j) {
      int c = col0 + tx * 4 + j;
      float v = acc[i][j] + bias[c];
      if (RELU) v = fmaxf(v, 0.f);
      C[(size_t)r * N + c] = v;
    }
  }
}

// ---------------- column stats: stats[0..N)=sum, stats[N..2N)=sumsq --------------------
template <int N>
__global__ __launch_bounds__(256) void colstats_kernel(
    const float* __restrict__ X, float* __restrict__ stats, int rows_per_block) {
  constexpr int NC = N / 256;
  int r0 = blockIdx.x * rows_per_block;
  int t = threadIdx.x;
  float s[NC], sq[NC];
#pragma unroll
  for (int i = 0; i < NC; ++i) { s[i] = 0.f; sq[i] = 0.f; }
  for (int r = r0; r < r0 + rows_per_block; ++r) {
    const float* row = X + (size_t)r * N;
#pragma unroll
    for (int i = 0; i < NC; ++i) {
      float v = row[t + i * 256];
      s[i] += v;
      sq[i] += v * v;
    }
  }
#pragma unroll
  for (int i = 0; i < NC; ++i) {
    atomicAdd(&stats[t + i * 256], s[i]);
    atomicAdd(&stats[N + t + i * 256], sq[i]);
  }
}

// ---------------- fold BN1 into W2: W2p = a1[k]*W2, bias2p = c1@W2 + b2 ----------------
__global__ __launch_bounds__(256) void fold_kernel(
    const float* __restrict__ W2, const float* __restrict__ b2,
    const float* __restrict__ g1, const float* __restrict__ beta1,
    const float* __restrict__ stats1, float* __restrict__ W2p,
    float* __restrict__ bias2p) {
  int j = blockIdx.x;  // output column, 512 blocks
  int t = threadIdx.x;
  __shared__ float red[256];
  float acc = 0.f;
  for (int k = t; k < N1_; k += 256) {
    float mean = stats1[k] * (1.f / B_);
    float var = stats1[N1_ + k] * (1.f / B_) - mean * mean;
    float a1 = g1[k] * rsqrtf(var + EPS_);
    float c1 = beta1[k] - mean * a1;
    float w = W2[(size_t)k * R_ + j];
    W2p[(size_t)k * R_ + j] = a1 * w;
    acc += c1 * w;
  }
  red[t] = acc;
  __syncthreads();
  for (int s2 = 128; s2 > 0; s2 >>= 1) {
    if (t < s2) red[t] += red[t + s2];
    __syncthreads();
  }
  if (t == 0) bias2p[j] = red[0] + b2[j];
}

// ---------------- final: logits = relu(BN2(z2)) @ W3 + b3 -----------------------------
__global__ __launch_bounds__(256) void final_kernel(
    const float* __restrict__ z2, const float* __restrict__ stats2,
    const float* __restrict__ g2, const float* __restrict__ beta2,
    const float* __restrict__ W3, const float* __restrict__ b3,
    float* __restrict__ out) {
  int wave = threadIdx.x >> 6;
  int lane = threadIdx.x & 63;
  int row = blockIdx.x * 4 + wave;
  const float* zr = z2 + (size_t)row * R_;
  float acc = 0.f;
#pragma unroll
  for (int i = 0; i < R_ / 64; ++i) {
    int j = lane + i * 64;
    float mean = stats2[j] * (1.f / B_);
    float var = stats2[R_ + j] * (1.f / B_) - mean * mean;
    float a2 = g2[j] * rsqrtf(var + EPS_);
    float c2 = beta2[j] - mean * a2;
    float h = fmaxf(zr[j] * a2 + c2, 0.f);
    acc += h * W3[j];
  }
  for (int off = 32; off > 0; off >>= 1) acc += __shfl_down(acc, off, 64);
  if (lane == 0) out[row] = acc + b3[0];
}

extern "C" void kernel_launch(void* const* d_in, const int* in_sizes, int n_in,
                              void* d_out, int out_size, void* d_ws, size_t ws_size,
                              hipStream_t stream) {
  const float* sv      = (const float*)d_in[0];
  const int*   qa_ids  = (const int*)d_in[1];
  const int*   qa_lens = (const int*)d_in[2];
  const float* emb     = (const float*)d_in[3];
  const float* W1      = (const float*)d_in[4];
  const float* b1      = (const float*)d_in[5];
  const float* g1      = (const float*)d_in[6];
  const float* beta1   = (const float*)d_in[7];
  const float* W2      = (const float*)d_in[8];
  const float* b2      = (const float*)d_in[9];
  const float* g2      = (const float*)d_in[10];
  const float* beta2   = (const float*)d_in[11];
  const float* W3      = (const float*)d_in[12];
  const float* b3      = (const float*)d_in[13];
  float* out = (float*)d_out;

  float* ws = (float*)d_ws;
  float* qas    = ws;                                  // B x 1224
  float* h1     = qas + (size_t)B_ * K1_;              // B x 1024
  float* W2p    = h1 + (size_t)B_ * N1_;               // 1024 x 512
  float* bias2p = W2p + (size_t)N1_ * R_;              // 512
  float* stats1 = bias2p + R_;                         // 2048
  float* stats2 = stats1 + 2 * N1_;                    // 1024
  float* z2     = stats2 + 2 * R_;                     // B x 512

  // zero the atomic-accumulated stats (ws is NOT re-poisoned between replays)
  hipMemsetAsync(stats1, 0, (2 * N1_ + 2 * R_) * sizeof(float), stream);

  pool_kernel<<<B_, 256, 0, stream>>>(sv, qa_ids, qa_lens, emb, qas);
  gemm_kernel<true><<<dim3(N1_ / 64, B_ / 64), 256, 0, stream>>>(qas, W1, b1, h1, B_, K1_, N1_);
  colstats_kernel<N1_><<<64, 256, 0, stream>>>(h1, stats1, B_ / 64);
  fold_kernel<<<R_, 256, 0, stream>>>(W2, b2, g1, beta1, stats1, W2p, bias2p);
  gemm_kernel<false><<<dim3(R_ / 64, B_ / 64), 256, 0, stream>>>(h1, W2p, bias2p, z2, B_, N1_, R_);
  colstats_kernel<R_><<<64, 256, 0, stream>>>(z2, stats2, B_ / 64);
  final_kernel<<<B_ / 4, 256, 0, stream>>>(z2, stats2, g2, beta2, W3, b3, out);
}

// Round 4
// 178.841 us; speedup vs baseline: 2.0355x; 2.0355x over previous
//
#include <hip/hip_runtime.h>
#include <hip/hip_bf16.h>

#define B_ 4096
#define L_ 128
#define D_ 100
#define S_ 1024
#define R_ 512
#define K1P_ 1248   // 2*D + S padded to multiple of 32
#define N1_ 1024    // 2*R
#define EPS_ 1e-5f
#define NBLK_ 64    // stats partial blocks

typedef short bf16x8 __attribute__((ext_vector_type(8)));
typedef short short4v __attribute__((ext_vector_type(4)));
typedef float f32x4 __attribute__((ext_vector_type(4)));

static __device__ __forceinline__ short f2bf(float x) {
  union { float f; unsigned u; } c; c.f = x;
  unsigned r = (c.u + 0x7fffu + ((c.u >> 16) & 1u)) >> 16;  // RNE
  return (short)r;
}
static __device__ __forceinline__ float bf2f(short x) {
  union { unsigned u; float f; } c; c.u = ((unsigned)(unsigned short)x) << 16;
  return c.f;
}

// swizzled chunk slot: bijective within row (2-bit XOR), 2-way banks = free
#define SWZ(r, c) ((c) ^ (((r) >> 1) & 3))

// ---------------- pool: ragged mean-pool + concat -> qas bf16 [B][1248] ----------------
__global__ __launch_bounds__(256) void pool_kernel(
    const float* __restrict__ sv, const int* __restrict__ qa_ids,
    const int* __restrict__ qa_lens, const float* __restrict__ emb,
    short* __restrict__ qas) {
  int b = blockIdx.x;
  int t = threadIdx.x;
  __shared__ int ids[L_ * 2];
  int len = qa_lens[b];
  ids[t] = qa_ids[(size_t)b * (L_ * 2) + t];
  __syncthreads();
  short* qrow = qas + (size_t)b * K1P_;
  if (t < 200) {
    int k = t / 100, d = t - k * 100;
    float acc = 0.f;
    for (int l = 0; l < len; ++l)
      acc += emb[(size_t)ids[l * 2 + k] * D_ + d];
    qrow[t] = f2bf(acc / (float)(len > 0 ? len : 1));
  }
  for (int i = t; i < S_; i += 256)
    qrow[200 + i] = f2bf(sv[(size_t)b * S_ + i]);
  if (t < K1P_ - 1224) qrow[1224 + t] = 0;  // zero K-pad
}

// ---------------- W1 [1224][1024] f32 -> W1t [1024][1248] bf16 (transposed, padded) ----
__global__ __launch_bounds__(256) void convert_w1_kernel(
    const float* __restrict__ W1, short* __restrict__ W1t) {
  __shared__ float tile[32][33];
  int n0 = blockIdx.x * 32, k0 = blockIdx.y * 32;
  int t = threadIdx.x;
#pragma unroll
  for (int p = 0; p < 4; ++p) {
    int kk = (t >> 5) + p * 8, nn = t & 31;
    int k = k0 + kk;
    tile[kk][nn] = (k < 1224) ? W1[(size_t)k * N1_ + n0 + nn] : 0.f;
  }
  __syncthreads();
#pragma unroll
  for (int p = 0; p < 4; ++p) {
    int nn = (t >> 5) + p * 8, kk = t & 31;
    W1t[(size_t)(n0 + nn) * K1P_ + k0 + kk] = f2bf(tile[kk][nn]);
  }
}

// ---------------- MFMA GEMM: C[M,N] = A[M,K]bf16 @ Bt[N,K]bf16^T + bias (+ReLU) -------
template <int BM, int BN, int WM, int WN, bool RELU, typename OutT>
__global__ __launch_bounds__(256) void mfma_gemm(
    const short* __restrict__ A, const short* __restrict__ Bt,
    const float* __restrict__ bias, OutT* __restrict__ C, int K, int N) {
  constexpr int FM = BM / WM / 16;
  constexpr int FN = BN / WN / 16;
  __shared__ short As[BM * 32];
  __shared__ short Bs[BN * 32];
  const int t = threadIdx.x;
  const int l = t & 63, w = t >> 6;
  const int wr = w / WN, wc = w % WN;
  const int row0 = blockIdx.y * BM, col0 = blockIdx.x * BN;
  f32x4 acc[FM][FN] = {};
  const int lrow = l & 15, lkc = l >> 4;
  for (int k0 = 0; k0 < K; k0 += 32) {
    for (int i = t; i < BM * 4; i += 256) {
      int r = i >> 2, kc = i & 3;
      bf16x8 v = *(const bf16x8*)(A + (size_t)(row0 + r) * K + k0 + kc * 8);
      *(bf16x8*)&As[r * 32 + (SWZ(r, kc) << 3)] = v;
    }
    for (int i = t; i < BN * 4; i += 256) {
      int r = i >> 2, kc = i & 3;
      bf16x8 v = *(const bf16x8*)(Bt + (size_t)(col0 + r) * K + k0 + kc * 8);
      *(bf16x8*)&Bs[r * 32 + (SWZ(r, kc) << 3)] = v;
    }
    __syncthreads();
    bf16x8 af[FM], bfr[FN];
#pragma unroll
    for (int m = 0; m < FM; ++m) {
      int r = wr * (BM / WM) + m * 16 + lrow;
      af[m] = *(const bf16x8*)&As[r * 32 + (SWZ(r, lkc) << 3)];
    }
#pragma unroll
    for (int n = 0; n < FN; ++n) {
      int r = wc * (BN / WN) + n * 16 + lrow;
      bfr[n] = *(const bf16x8*)&Bs[r * 32 + (SWZ(r, lkc) << 3)];
    }
#pragma unroll
    for (int m = 0; m < FM; ++m)
#pragma unroll
      for (int n = 0; n < FN; ++n)
        acc[m][n] = __builtin_amdgcn_mfma_f32_16x16x32_bf16(af[m], bfr[n], acc[m][n], 0, 0, 0);
    __syncthreads();
  }
#pragma unroll
  for (int m = 0; m < FM; ++m) {
#pragma unroll
    for (int n = 0; n < FN; ++n) {
      int col = col0 + wc * (BN / WN) + n * 16 + lrow;
      float bv = bias[col];
#pragma unroll
      for (int j = 0; j < 4; ++j) {
        int row = row0 + wr * (BM / WM) + m * 16 + (l >> 4) * 4 + j;
        float v = acc[m][n][j] + bv;
        if (RELU) v = fmaxf(v, 0.f);
        if constexpr (sizeof(OutT) == 2) C[(size_t)row * N + col] = f2bf(v);
        else                             C[(size_t)row * N + col] = v;
      }
    }
  }
}

// ---------------- partial column stats (deterministic, no atomics) ---------------------
// part[blk][0..N) = sum, part[blk][N..2N) = sumsq over this block's rows
__global__ __launch_bounds__(256) void partstats_bf16(
    const short* __restrict__ X, float* __restrict__ part, int rows) {
  int t = threadIdx.x, blk = blockIdx.x;
  int r0 = blk * rows;
  int c = t * 4;
  float s[4] = {}, q[4] = {};
  for (int r = r0; r < r0 + rows; ++r) {
    short4v v = *(const short4v*)&X[(size_t)r * N1_ + c];
#pragma unroll
    for (int j = 0; j < 4; ++j) {
      float f = bf2f(v[j]);
      s[j] += f; q[j] += f * f;
    }
  }
  float* pb = part + (size_t)blk * 2 * N1_;
#pragma unroll
  for (int j = 0; j < 4; ++j) {
    pb[c + j] = s[j];
    pb[N1_ + c + j] = q[j];
  }
}

__global__ __launch_bounds__(256) void partstats_f32(
    const float* __restrict__ X, float* __restrict__ part, int rows) {
  int t = threadIdx.x, blk = blockIdx.x;
  int r0 = blk * rows;
  int c = t * 2;
  float s0 = 0, s1 = 0, q0 = 0, q1 = 0;
  for (int r = r0; r < r0 + rows; ++r) {
    float2 v = *(const float2*)&X[(size_t)r * R_ + c];
    s0 += v.x; q0 += v.x * v.x;
    s1 += v.y; q1 += v.y * v.y;
  }
  float* pb = part + (size_t)blk * 2 * R_;
  pb[c] = s0; pb[c + 1] = s1;
  pb[R_ + c] = q0; pb[R_ + c + 1] = q1;
}

// stats[s] = sum over NBLK_ blocks of part[b][s]  (deterministic order)
__global__ __launch_bounds__(256) void reduce_stats(
    const float* __restrict__ part, float* __restrict__ stats, int nslots) {
  int s = blockIdx.x * 256 + threadIdx.x;
  if (s >= nslots) return;
  float a = 0.f;
  for (int b = 0; b < NBLK_; ++b) a += part[(size_t)b * nslots + s];
  stats[s] = a;
}

// ---------------- fold BN1 into W2: W2pt[j][k] = a1[k]*W2[k][j] bf16; bias2p f32 -------
__global__ __launch_bounds__(256) void fold_kernel(
    const float* __restrict__ W2, const float* __restrict__ b2,
    const float* __restrict__ g1, const float* __restrict__ beta1,
    const float* __restrict__ stats1, short* __restrict__ W2pt,
    float* __restrict__ bias2p) {
  int j = blockIdx.x;
  int t = threadIdx.x;
  __shared__ float red[256];
  float acc = 0.f;
  for (int k = t; k < N1_; k += 256) {
    float mean = stats1[k] * (1.f / B_);
    float var = stats1[N1_ + k] * (1.f / B_) - mean * mean;
    float a1 = g1[k] * rsqrtf(var + EPS_);
    float c1 = beta1[k] - mean * a1;
    float w = W2[(size_t)k * R_ + j];
    W2pt[(size_t)j * N1_ + k] = f2bf(a1 * w);
    acc += c1 * w;
  }
  red[t] = acc;
  __syncthreads();
  for (int s2 = 128; s2 > 0; s2 >>= 1) {
    if (t < s2) red[t] += red[t + s2];
    __syncthreads();
  }
  if (t == 0) bias2p[j] = red[0] + b2[j];
}

// ---------------- final: logits = relu(BN2(z2)) @ W3 + b3 ------------------------------
__global__ __launch_bounds__(256) void final_kernel(
    const float* __restrict__ z2, const float* __restrict__ stats2,
    const float* __restrict__ g2, const float* __restrict__ beta2,
    const float* __restrict__ W3, const float* __restrict__ b3,
    float* __restrict__ out) {
  int wave = threadIdx.x >> 6;
  int lane = threadIdx.x & 63;
  int row = blockIdx.x * 4 + wave;
  const float* zr = z2 + (size_t)row * R_;
  float acc = 0.f;
#pragma unroll
  for (int i = 0; i < R_ / 64; ++i) {
    int j = lane + i * 64;
    float mean = stats2[j] * (1.f / B_);
    float var = stats2[R_ + j] * (1.f / B_) - mean * mean;
    float a2 = g2[j] * rsqrtf(var + EPS_);
    float c2 = beta2[j] - mean * a2;
    float h = fmaxf(zr[j] * a2 + c2, 0.f);
    acc += h * W3[j];
  }
  for (int off = 32; off > 0; off >>= 1) acc += __shfl_down(acc, off, 64);
  if (lane == 0) out[row] = acc + b3[0];
}

extern "C" void kernel_launch(void* const* d_in, const int* in_sizes, int n_in,
                              void* d_out, int out_size, void* d_ws, size_t ws_size,
                              hipStream_t stream) {
  const float* sv      = (const float*)d_in[0];
  const int*   qa_ids  = (const int*)d_in[1];
  const int*   qa_lens = (const int*)d_in[2];
  const float* emb     = (const float*)d_in[3];
  const float* W1      = (const float*)d_in[4];
  const float* b1      = (const float*)d_in[5];
  const float* g1      = (const float*)d_in[6];
  const float* beta1   = (const float*)d_in[7];
  const float* W2      = (const float*)d_in[8];
  const float* b2      = (const float*)d_in[9];
  const float* g2      = (const float*)d_in[10];
  const float* beta2   = (const float*)d_in[11];
  const float* W3      = (const float*)d_in[12];
  const float* b3      = (const float*)d_in[13];
  float* out = (float*)d_out;

  char* p = (char*)d_ws;
  short* qas    = (short*)p; p += (size_t)B_ * K1P_ * 2;        // bf16 [4096][1248]
  short* W1t    = (short*)p; p += (size_t)N1_ * K1P_ * 2;       // bf16 [1024][1248]
  short* h1     = (short*)p; p += (size_t)B_ * N1_ * 2;         // bf16 [4096][1024]
  short* W2pt   = (short*)p; p += (size_t)R_ * N1_ * 2;         // bf16 [512][1024]
  float* bias2p = (float*)p; p += R_ * 4;
  float* stats1 = (float*)p; p += 2 * N1_ * 4;
  float* stats2 = (float*)p; p += 2 * R_ * 4;
  float* part1  = (float*)p; p += (size_t)NBLK_ * 2 * N1_ * 4;  // [64][2048]
  float* part2  = (float*)p; p += (size_t)NBLK_ * 2 * R_ * 4;   // [64][1024]
  float* z2     = (float*)p;                                    // f32 [4096][512]

  convert_w1_kernel<<<dim3(N1_ / 32, K1P_ / 32), 256, 0, stream>>>(W1, W1t);
  pool_kernel<<<B_, 256, 0, stream>>>(sv, qa_ids, qa_lens, emb, qas);
  // GEMM1: [4096,1248] @ [1248,1024] -> h1 bf16, +b1, ReLU
  mfma_gemm<128, 64, 2, 2, true, short>
      <<<dim3(N1_ / 64, B_ / 128), 256, 0, stream>>>(qas, W1t, b1, h1, K1P_, N1_);
  partstats_bf16<<<NBLK_, 256, 0, stream>>>(h1, part1, B_ / NBLK_);
  reduce_stats<<<(2 * N1_ + 255) / 256, 256, 0, stream>>>(part1, stats1, 2 * N1_);
  fold_kernel<<<R_, 256, 0, stream>>>(W2, b2, g1, beta1, stats1, W2pt, bias2p);
  // GEMM2: [4096,1024] @ [1024,512] -> z2 f32, +bias2p
  mfma_gemm<64, 64, 2, 2, false, float>
      <<<dim3(R_ / 64, B_ / 64), 256, 0, stream>>>(h1, W2pt, bias2p, z2, N1_, R_);
  partstats_f32<<<NBLK_, 256, 0, stream>>>(z2, part2, B_ / NBLK_);
  reduce_stats<<<(2 * R_ + 255) / 256, 256, 0, stream>>>(part2, stats2, 2 * R_);
  final_kernel<<<B_ / 4, 256, 0, stream>>>(z2, stats2, g2, beta2, W3, b3, out);
}

// Round 5
// 169.957 us; speedup vs baseline: 2.1419x; 1.0523x over previous
//
#include <hip/hip_runtime.h>
#include <hip/hip_bf16.h>

#define B_ 4096
#define L_ 128
#define D_ 100
#define S_ 1024
#define R_ 512
#define K1P_ 1248   // 2*D + S padded to multiple of 32
#define N1_ 1024    // 2*R
#define EPS_ 1e-5f

typedef short bf16x8 __attribute__((ext_vector_type(8)));
typedef short short4v __attribute__((ext_vector_type(4)));
typedef float f32x4 __attribute__((ext_vector_type(4)));

static __device__ __forceinline__ short f2bf(float x) {
  union { float f; unsigned u; } c; c.f = x;
  unsigned r = (c.u + 0x7fffu + ((c.u >> 16) & 1u)) >> 16;  // RNE
  return (short)r;
}
static __device__ __forceinline__ float bf2f(short x) {
  union { unsigned u; float f; } c; c.u = ((unsigned)(unsigned short)x) << 16;
  return c.f;
}

// swizzled chunk slot: bijective within row (2-bit XOR), 2-way banks = free
#define SWZ(r, c) ((c) ^ (((r) >> 1) & 3))

// ---------------- pool: ragged mean-pool + concat -> qas bf16 [B][1248] ----------------
// wave w handles rows r = w, w+4, ... of the 2*len (l,k)-pairs; k = w&1 is wave-fixed.
// lanes 0..49 each hold d = {2*lane, 2*lane+1} via float2 loads (one row per wave-instr).
__global__ __launch_bounds__(256) void pool_kernel(
    const float* __restrict__ sv, const int* __restrict__ qa_ids,
    const int* __restrict__ qa_lens, const float* __restrict__ emb,
    short* __restrict__ qas) {
  int b = blockIdx.x;
  int t = threadIdx.x;
  __shared__ int ids[L_ * 2];
  __shared__ float partial[4][D_];
  int len = qa_lens[b];
  ids[t] = qa_ids[(size_t)b * (L_ * 2) + t];
  __syncthreads();
  int w = t >> 6, l = t & 63;
  if (l < 50) {
    float a0 = 0.f, a1 = 0.f;
    for (int r = w; r < 2 * len; r += 4) {
      const float* row = emb + (size_t)ids[r] * D_;
      float2 v = *reinterpret_cast<const float2*>(row + l * 2);
      a0 += v.x; a1 += v.y;
    }
    partial[w][l * 2] = a0;
    partial[w][l * 2 + 1] = a1;
  }
  __syncthreads();
  short* qrow = qas + (size_t)b * K1P_;
  if (t < 200) {
    int k = t / 100, d = t - k * 100;
    float s = partial[k][d] + partial[k + 2][d];  // waves k and k+2 hold parity k
    qrow[t] = f2bf(s / (float)(len > 0 ? len : 1));
  }
  {  // statement copy: 256 threads x float4 -> 4x bf16
    float4 v = *reinterpret_cast<const float4*>(sv + (size_t)b * S_ + t * 4);
    short4v o;
    o[0] = f2bf(v.x); o[1] = f2bf(v.y); o[2] = f2bf(v.z); o[3] = f2bf(v.w);
    *(short4v*)&qrow[200 + t * 4] = o;
  }
  if (t < K1P_ - 1224) qrow[1224 + t] = 0;  // zero K-pad
}

// ---------------- W1 [1224][1024] f32 -> W1t [1024][1248] bf16 (transposed, padded) ----
__global__ __launch_bounds__(256) void convert_w1_kernel(
    const float* __restrict__ W1, short* __restrict__ W1t) {
  __shared__ float tile[32][33];
  int n0 = blockIdx.x * 32, k0 = blockIdx.y * 32;
  int t = threadIdx.x;
#pragma unroll
  for (int p = 0; p < 4; ++p) {
    int kk = (t >> 5) + p * 8, nn = t & 31;
    int k = k0 + kk;
    tile[kk][nn] = (k < 1224) ? W1[(size_t)k * N1_ + n0 + nn] : 0.f;
  }
  __syncthreads();
#pragma unroll
  for (int p = 0; p < 4; ++p) {
    int nn = (t >> 5) + p * 8, kk = t & 31;
    W1t[(size_t)(n0 + nn) * K1P_ + k0 + kk] = f2bf(tile[kk][nn]);
  }
}

// ---------------- MFMA GEMM + fused deterministic column partial-stats -----------------
// C[M,N] = A[M,K]bf16 @ Bt[N,K]^T + bias (+ReLU). part[by][0..N)=colsum, [N..2N)=colsumsq
// over this block's BM rows (stats taken over the VALUES AS STORED: bf16-rounded if
// OutT==short). Each (by,col) slot written by exactly one block -> deterministic.
template <int BM, int BN, int WM, int WN, bool RELU, typename OutT>
__global__ __launch_bounds__(256) void mfma_gemm(
    const short* __restrict__ A, const short* __restrict__ Bt,
    const float* __restrict__ bias, OutT* __restrict__ C,
    float* __restrict__ part, int K, int N) {
  constexpr int FM = BM / WM / 16;
  constexpr int FN = BN / WN / 16;
  __shared__ short As[BM * 32];
  __shared__ short Bs[BN * 32];
  __shared__ float sred[WM][WN][FN][16];
  __shared__ float qred[WM][WN][FN][16];
  const int t = threadIdx.x;
  const int l = t & 63, w = t >> 6;
  const int wr = w / WN, wc = w % WN;
  const int row0 = blockIdx.y * BM, col0 = blockIdx.x * BN;
  f32x4 acc[FM][FN] = {};
  const int lrow = l & 15, lkc = l >> 4;
  for (int k0 = 0; k0 < K; k0 += 32) {
    for (int i = t; i < BM * 4; i += 256) {
      int r = i >> 2, kc = i & 3;
      bf16x8 v = *(const bf16x8*)(A + (size_t)(row0 + r) * K + k0 + kc * 8);
      *(bf16x8*)&As[r * 32 + (SWZ(r, kc) << 3)] = v;
    }
    for (int i = t; i < BN * 4; i += 256) {
      int r = i >> 2, kc = i & 3;
      bf16x8 v = *(const bf16x8*)(Bt + (size_t)(col0 + r) * K + k0 + kc * 8);
      *(bf16x8*)&Bs[r * 32 + (SWZ(r, kc) << 3)] = v;
    }
    __syncthreads();
    bf16x8 af[FM], bfr[FN];
#pragma unroll
    for (int m = 0; m < FM; ++m) {
      int r = wr * (BM / WM) + m * 16 + lrow;
      af[m] = *(const bf16x8*)&As[r * 32 + (SWZ(r, lkc) << 3)];
    }
#pragma unroll
    for (int n = 0; n < FN; ++n) {
      int r = wc * (BN / WN) + n * 16 + lrow;
      bfr[n] = *(const bf16x8*)&Bs[r * 32 + (SWZ(r, lkc) << 3)];
    }
#pragma unroll
    for (int m = 0; m < FM; ++m)
#pragma unroll
      for (int n = 0; n < FN; ++n)
        acc[m][n] = __builtin_amdgcn_mfma_f32_16x16x32_bf16(af[m], bfr[n], acc[m][n], 0, 0, 0);
    __syncthreads();
  }
  // epilogue: C/D layout col = lane&15, row = (lane>>4)*4 + j; accumulate stats
  float ss[FN], qq[FN];
#pragma unroll
  for (int n = 0; n < FN; ++n) { ss[n] = 0.f; qq[n] = 0.f; }
#pragma unroll
  for (int m = 0; m < FM; ++m) {
#pragma unroll
    for (int n = 0; n < FN; ++n) {
      int col = col0 + wc * (BN / WN) + n * 16 + lrow;
      float bv = bias[col];
#pragma unroll
      for (int j = 0; j < 4; ++j) {
        int row = row0 + wr * (BM / WM) + m * 16 + (l >> 4) * 4 + j;
        float v = acc[m][n][j] + bv;
        if (RELU) v = fmaxf(v, 0.f);
        float f;
        if constexpr (sizeof(OutT) == 2) {
          short vb = f2bf(v);
          C[(size_t)row * N + col] = vb;
          f = bf2f(vb);
        } else {
          C[(size_t)row * N + col] = v;
          f = v;
        }
        ss[n] += f;
        qq[n] += f * f;
      }
    }
  }
  // reduce the 4 lane-groups sharing a column, then across row-waves via LDS
#pragma unroll
  for (int n = 0; n < FN; ++n) {
    ss[n] += __shfl_xor(ss[n], 16);
    ss[n] += __shfl_xor(ss[n], 32);
    qq[n] += __shfl_xor(qq[n], 16);
    qq[n] += __shfl_xor(qq[n], 32);
  }
  if (l < 16) {
#pragma unroll
    for (int n = 0; n < FN; ++n) {
      sred[wr][wc][n][l] = ss[n];
      qred[wr][wc][n][l] = qq[n];
    }
  }
  __syncthreads();
  if (t < WN * FN * 16) {
    int c16 = t & 15, n = (t >> 4) % FN, wcc = t / (16 * FN);
    float s = 0.f, q = 0.f;
#pragma unroll
    for (int r = 0; r < WM; ++r) { s += sred[r][wcc][n][c16]; q += qred[r][wcc][n][c16]; }
    int col = col0 + wcc * (BN / WN) + n * 16 + c16;
    part[(size_t)blockIdx.y * 2 * N + col] = s;
    part[(size_t)blockIdx.y * 2 * N + N + col] = q;
  }
}

// stats[s] = sum over nblk blocks of part[b][s]  (deterministic order)
__global__ __launch_bounds__(256) void reduce_stats(
    const float* __restrict__ part, float* __restrict__ stats, int nslots, int nblk) {
  int s = blockIdx.x * 256 + threadIdx.x;
  if (s >= nslots) return;
  float a = 0.f;
  for (int b = 0; b < nblk; ++b) a += part[(size_t)b * nslots + s];
  stats[s] = a;
}

// ---------------- fold BN1 into W2: W2pt[j][k] = a1[k]*W2[k][j] bf16; bias2p f32 -------
__global__ __launch_bounds__(256) void fold_kernel(
    const float* __restrict__ W2, const float* __restrict__ b2,
    const float* __restrict__ g1, const float* __restrict__ beta1,
    const float* __restrict__ stats1, short* __restrict__ W2pt,
    float* __restrict__ bias2p) {
  int j = blockIdx.x;
  int t = threadIdx.x;
  __shared__ float red[256];
  float acc = 0.f;
  for (int k = t; k < N1_; k += 256) {
    float mean = stats1[k] * (1.f / B_);
    float var = stats1[N1_ + k] * (1.f / B_) - mean * mean;
    float a1 = g1[k] * rsqrtf(var + EPS_);
    float c1 = beta1[k] - mean * a1;
    float w = W2[(size_t)k * R_ + j];
    W2pt[(size_t)j * N1_ + k] = f2bf(a1 * w);
    acc += c1 * w;
  }
  red[t] = acc;
  __syncthreads();
  for (int s2 = 128; s2 > 0; s2 >>= 1) {
    if (t < s2) red[t] += red[t + s2];
    __syncthreads();
  }
  if (t == 0) bias2p[j] = red[0] + b2[j];
}

// ---------------- final: logits = relu(BN2(z2)) @ W3 + b3 ------------------------------
__global__ __launch_bounds__(256) void final_kernel(
    const float* __restrict__ z2, const float* __restrict__ stats2,
    const float* __restrict__ g2, const float* __restrict__ beta2,
    const float* __restrict__ W3, const float* __restrict__ b3,
    float* __restrict__ out) {
  int wave = threadIdx.x >> 6;
  int lane = threadIdx.x & 63;
  int row = blockIdx.x * 4 + wave;
  const float* zr = z2 + (size_t)row * R_;
  float acc = 0.f;
#pragma unroll
  for (int i = 0; i < R_ / 64; ++i) {
    int j = lane + i * 64;
    float mean = stats2[j] * (1.f / B_);
    float var = stats2[R_ + j] * (1.f / B_) - mean * mean;
    float a2 = g2[j] * rsqrtf(var + EPS_);
    float c2 = beta2[j] - mean * a2;
    float h = fmaxf(zr[j] * a2 + c2, 0.f);
    acc += h * W3[j];
  }
  for (int off = 32; off > 0; off >>= 1) acc += __shfl_down(acc, off, 64);
  if (lane == 0) out[row] = acc + b3[0];
}

extern "C" void kernel_launch(void* const* d_in, const int* in_sizes, int n_in,
                              void* d_out, int out_size, void* d_ws, size_t ws_size,
                              hipStream_t stream) {
  const float* sv      = (const float*)d_in[0];
  const int*   qa_ids  = (const int*)d_in[1];
  const int*   qa_lens = (const int*)d_in[2];
  const float* emb     = (const float*)d_in[3];
  const float* W1      = (const float*)d_in[4];
  const float* b1      = (const float*)d_in[5];
  const float* g1      = (const float*)d_in[6];
  const float* beta1   = (const float*)d_in[7];
  const float* W2      = (const float*)d_in[8];
  const float* b2      = (const float*)d_in[9];
  const float* g2      = (const float*)d_in[10];
  const float* beta2   = (const float*)d_in[11];
  const float* W3      = (const float*)d_in[12];
  const float* b3      = (const float*)d_in[13];
  float* out = (float*)d_out;

  char* p = (char*)d_ws;
  short* qas    = (short*)p; p += (size_t)B_ * K1P_ * 2;        // bf16 [4096][1248]
  short* W1t    = (short*)p; p += (size_t)N1_ * K1P_ * 2;       // bf16 [1024][1248]
  short* h1     = (short*)p; p += (size_t)B_ * N1_ * 2;         // bf16 [4096][1024]
  short* W2pt   = (short*)p; p += (size_t)R_ * N1_ * 2;         // bf16 [512][1024]
  float* bias2p = (float*)p; p += R_ * 4;
  float* stats1 = (float*)p; p += 2 * N1_ * 4;
  float* stats2 = (float*)p; p += 2 * R_ * 4;
  float* part1  = (float*)p; p += (size_t)32 * 2 * N1_ * 4;     // [32 row-tiles][2048]
  float* part2  = (float*)p; p += (size_t)64 * 2 * R_ * 4;      // [64 row-tiles][1024]
  float* z2     = (float*)p;                                    // f32 [4096][512]

  convert_w1_kernel<<<dim3(N1_ / 32, K1P_ / 32), 256, 0, stream>>>(W1, W1t);
  pool_kernel<<<B_, 256, 0, stream>>>(sv, qa_ids, qa_lens, emb, qas);
  // GEMM1: [4096,1248] @ [1248,1024] -> h1 bf16, +b1, ReLU; partial stats per row-tile
  mfma_gemm<128, 64, 2, 2, true, short>
      <<<dim3(N1_ / 64, B_ / 128), 256, 0, stream>>>(qas, W1t, b1, h1, part1, K1P_, N1_);
  reduce_stats<<<(2 * N1_ + 255) / 256, 256, 0, stream>>>(part1, stats1, 2 * N1_, B_ / 128);
  fold_kernel<<<R_, 256, 0, stream>>>(W2, b2, g1, beta1, stats1, W2pt, bias2p);
  // GEMM2: [4096,1024] @ [1024,512] -> z2 f32, +bias2p; partial stats per row-tile
  mfma_gemm<64, 64, 2, 2, false, float>
      <<<dim3(R_ / 64, B_ / 64), 256, 0, stream>>>(h1, W2pt, bias2p, z2, part2, N1_, R_);
  reduce_stats<<<(2 * R_ + 255) / 256, 256, 0, stream>>>(part2, stats2, 2 * R_, B_ / 64);
  final_kernel<<<B_ / 4, 256, 0, stream>>>(z2, stats2, g2, beta2, W3, b3, out);
}

// Round 6
// 140.363 us; speedup vs baseline: 2.5935x; 1.2108x over previous
//
#include <hip/hip_runtime.h>
#include <hip/hip_bf16.h>

#define B_ 4096
#define L_ 128
#define D_ 100
#define S_ 1024
#define R_ 512
#define K1P_ 1248   // 2*D + S padded to multiple of 32
#define N1_ 1024    // 2*R
#define EPS_ 1e-5f

typedef short bf16x8 __attribute__((ext_vector_type(8)));
typedef short short4v __attribute__((ext_vector_type(4)));
typedef float f32x4 __attribute__((ext_vector_type(4)));

static __device__ __forceinline__ short f2bf(float x) {
  union { float f; unsigned u; } c; c.f = x;
  unsigned r = (c.u + 0x7fffu + ((c.u >> 16) & 1u)) >> 16;  // RNE
  return (short)r;
}
static __device__ __forceinline__ float bf2f(short x) {
  union { unsigned u; float f; } c; c.u = ((unsigned)(unsigned short)x) << 16;
  return c.f;
}

// chunk swizzle (involution): LDS slot c of row r holds global chunk c ^ ((r>>1)&3)
#define SWZ(r, c) ((c) ^ (((r) >> 1) & 3))

// ---------------- prep: pool (blocks < B_) + W1 transpose/convert (blocks >= B_) -------
__global__ __launch_bounds__(256) void prep_kernel(
    const float* __restrict__ sv, const int* __restrict__ qa_ids,
    const int* __restrict__ qa_lens, const float* __restrict__ emb,
    const float* __restrict__ W1, short* __restrict__ qas,
    short* __restrict__ W1t) {
  int t = threadIdx.x;
  if (blockIdx.x < B_) {
    int b = blockIdx.x;
    __shared__ int ids[L_ * 2];
    __shared__ __align__(16) float partial[4][D_];
    int len = qa_lens[b];
    ids[t] = qa_ids[(size_t)b * (L_ * 2) + t];
    __syncthreads();
    int w = t >> 6, l = t & 63;
    if (l < 25) {  // 25 lanes x float4 = one 400B emb row per wave-instruction
      float4 a = {0.f, 0.f, 0.f, 0.f};
      for (int r = w; r < 2 * len; r += 4) {
        const float* row = emb + (size_t)ids[r] * D_;
        float4 v = *reinterpret_cast<const float4*>(row + l * 4);
        a.x += v.x; a.y += v.y; a.z += v.z; a.w += v.w;
      }
      *reinterpret_cast<float4*>(&partial[w][l * 4]) = a;
    }
    __syncthreads();
    short* qrow = qas + (size_t)b * K1P_;
    if (t < 200) {
      int k = t / 100, d = t - k * 100;
      float s = partial[k][d] + partial[k + 2][d];  // waves k, k+2 hold parity k
      qrow[t] = f2bf(s / (float)(len > 0 ? len : 1));
    }
    {  // statement copy: 256 threads x float4 -> 4x bf16
      float4 v = *reinterpret_cast<const float4*>(sv + (size_t)b * S_ + t * 4);
      short4v o;
      o[0] = f2bf(v.x); o[1] = f2bf(v.y); o[2] = f2bf(v.z); o[3] = f2bf(v.w);
      *(short4v*)&qrow[200 + t * 4] = o;
    }
    if (t < K1P_ - 1224) qrow[1224 + t] = 0;  // zero K-pad
  } else {
    // W1 [1224][1024] f32 -> W1t [1024][1248] bf16 (transposed, zero-padded)
    __shared__ float tile[32][33];
    int bx = blockIdx.x - B_;
    int n0 = (bx & 31) * 32, k0 = (bx >> 5) * 32;
#pragma unroll
    for (int p = 0; p < 4; ++p) {
      int kk = (t >> 5) + p * 8, nn = t & 31;
      int k = k0 + kk;
      tile[kk][nn] = (k < 1224) ? W1[(size_t)k * N1_ + n0 + nn] : 0.f;
    }
    __syncthreads();
#pragma unroll
    for (int p = 0; p < 4; ++p) {
      int nn = (t >> 5) + p * 8, kk = t & 31;
      W1t[(size_t)(n0 + nn) * K1P_ + k0 + kk] = f2bf(tile[kk][nn]);
    }
  }
}

// ---------------- async stage: ROWS x 32 bf16 tile -> LDS via global_load_lds ----------
// LDS layout linear (HW writes wave_base + lane*16); swizzle applied to the GLOBAL
// source chunk (kc = SWZ(r,c), involution) so the read path is unchanged.
template <int ROWS>
static __device__ __forceinline__ void stage_tile(
    const short* __restrict__ gp, int stride, int k0, short* lds, int w, int l) {
#pragma unroll
  for (int p = 0; p < ROWS / 64; ++p) {
    int off16 = p * 256 + w * 64 + l;  // 16B-chunk index within tile
    int r = off16 >> 2;
    int c = off16 & 3;
    int kc = SWZ(r, c);
    const short* g = gp + (size_t)r * stride + k0 + kc * 8;
    __builtin_amdgcn_global_load_lds(
        (const __attribute__((address_space(1))) void*)g,
        (__attribute__((address_space(3))) void*)(lds + p * 2048 + w * 512),
        16, 0, 0);
  }
}

// ---------------- MFMA GEMM (2-phase async pipeline) + fused column partial-stats ------
template <int BM, int BN, int WM, int WN, bool RELU, typename OutT>
__global__ __launch_bounds__(256) void mfma_gemm(
    const short* __restrict__ A, const short* __restrict__ Bt,
    const float* __restrict__ bias, OutT* __restrict__ C,
    float* __restrict__ part, int K, int N) {
  constexpr int FM = BM / WM / 16;
  constexpr int FN = BN / WN / 16;
  __shared__ short As[2][BM * 32];
  __shared__ short Bs[2][BN * 32];
  __shared__ float sred[WM][WN][FN][16];
  __shared__ float qred[WM][WN][FN][16];
  const int t = threadIdx.x;
  const int l = t & 63, w = t >> 6;
  const int wr = w / WN, wc = w % WN;
  const int row0 = blockIdx.y * BM, col0 = blockIdx.x * BN;
  const short* Ab = A + (size_t)row0 * K;
  const short* Bb = Bt + (size_t)col0 * K;
  f32x4 acc[FM][FN] = {};
  const int lrow = l & 15, lkc = l >> 4;
  const int nt = K / 32;
  // prologue: stage tile 0, drain, barrier
  stage_tile<BM>(Ab, K, 0, As[0], w, l);
  stage_tile<BN>(Bb, K, 0, Bs[0], w, l);
  __syncthreads();  // vmcnt(0) + barrier
  for (int ts = 0; ts < nt; ++ts) {
    const int cur = ts & 1;
    if (ts + 1 < nt) {  // issue next tile's async loads (other buffer)
      stage_tile<BM>(Ab, K, (ts + 1) * 32, As[cur ^ 1], w, l);
      stage_tile<BN>(Bb, K, (ts + 1) * 32, Bs[cur ^ 1], w, l);
    }
    bf16x8 af[FM], bfr[FN];
#pragma unroll
    for (int m = 0; m < FM; ++m) {
      int r = wr * (BM / WM) + m * 16 + lrow;
      af[m] = *(const bf16x8*)&As[cur][r * 32 + (SWZ(r, lkc) << 3)];
    }
#pragma unroll
    for (int n = 0; n < FN; ++n) {
      int r = wc * (BN / WN) + n * 16 + lrow;
      bfr[n] = *(const bf16x8*)&Bs[cur][r * 32 + (SWZ(r, lkc) << 3)];
    }
#pragma unroll
    for (int m = 0; m < FM; ++m)
#pragma unroll
      for (int n = 0; n < FN; ++n)
        acc[m][n] = __builtin_amdgcn_mfma_f32_16x16x32_bf16(af[m], bfr[n], acc[m][n], 0, 0, 0);
    __syncthreads();  // drains prefetch (vmcnt 0) + protects buffer reuse
  }
  // epilogue: C/D layout col = lane&15, row = (lane>>4)*4 + j; fused stats
  float ss[FN], qq[FN];
#pragma unroll
  for (int n = 0; n < FN; ++n) { ss[n] = 0.f; qq[n] = 0.f; }
#pragma unroll
  for (int m = 0; m < FM; ++m) {
#pragma unroll
    for (int n = 0; n < FN; ++n) {
      int col = col0 + wc * (BN / WN) + n * 16 + lrow;
      float bv = bias[col];
#pragma unroll
      for (int j = 0; j < 4; ++j) {
        int row = row0 + wr * (BM / WM) + m * 16 + (l >> 4) * 4 + j;
        float v = acc[m][n][j] + bv;
        if (RELU) v = fmaxf(v, 0.f);
        float f;
        if constexpr (sizeof(OutT) == 2) {
          short vb = f2bf(v);
          C[(size_t)row * N + col] = vb;
          f = bf2f(vb);
        } else {
          C[(size_t)row * N + col] = v;
          f = v;
        }
        ss[n] += f;
        qq[n] += f * f;
      }
    }
  }
#pragma unroll
  for (int n = 0; n < FN; ++n) {
    ss[n] += __shfl_xor(ss[n], 16);
    ss[n] += __shfl_xor(ss[n], 32);
    qq[n] += __shfl_xor(qq[n], 16);
    qq[n] += __shfl_xor(qq[n], 32);
  }
  if (l < 16) {
#pragma unroll
    for (int n = 0; n < FN; ++n) {
      sred[wr][wc][n][l] = ss[n];
      qred[wr][wc][n][l] = qq[n];
    }
  }
  __syncthreads();
  if (t < WN * FN * 16) {
    int c16 = t & 15, n = (t >> 4) % FN, wcc = t / (16 * FN);
    float s = 0.f, q = 0.f;
#pragma unroll
    for (int r = 0; r < WM; ++r) { s += sred[r][wcc][n][c16]; q += qred[r][wcc][n][c16]; }
    int col = col0 + wcc * (BN / WN) + n * 16 + c16;
    part[(size_t)blockIdx.y * 2 * N + col] = s;
    part[(size_t)blockIdx.y * 2 * N + N + col] = q;
  }
}

// stats[s] = sum over nblk blocks of part[b][s]  (deterministic order)
__global__ __launch_bounds__(256) void reduce_stats(
    const float* __restrict__ part, float* __restrict__ stats, int nslots, int nblk) {
  int s = blockIdx.x * 256 + threadIdx.x;
  if (s >= nslots) return;
  float a = 0.f;
  for (int b = 0; b < nblk; ++b) a += part[(size_t)b * nslots + s];
  stats[s] = a;
}

// ---------------- fold BN1 into W2: W2pt[j][k] = a1[k]*W2[k][j] bf16; bias2p f32 -------
__global__ __launch_bounds__(256) void fold_kernel(
    const float* __restrict__ W2, const float* __restrict__ b2,
    const float* __restrict__ g1, const float* __restrict__ beta1,
    const float* __restrict__ stats1, short* __restrict__ W2pt,
    float* __restrict__ bias2p) {
  int j = blockIdx.x;
  int t = threadIdx.x;
  __shared__ float red[256];
  float acc = 0.f;
  for (int k = t; k < N1_; k += 256) {
    float mean = stats1[k] * (1.f / B_);
    float var = stats1[N1_ + k] * (1.f / B_) - mean * mean;
    float a1 = g1[k] * rsqrtf(var + EPS_);
    float c1 = beta1[k] - mean * a1;
    float w = W2[(size_t)k * R_ + j];
    W2pt[(size_t)j * N1_ + k] = f2bf(a1 * w);
    acc += c1 * w;
  }
  red[t] = acc;
  __syncthreads();
  for (int s2 = 128; s2 > 0; s2 >>= 1) {
    if (t < s2) red[t] += red[t + s2];
    __syncthreads();
  }
  if (t == 0) bias2p[j] = red[0] + b2[j];
}

// ---------------- final: logits = relu(BN2(z2)) @ W3 + b3 ------------------------------
__global__ __launch_bounds__(256) void final_kernel(
    const float* __restrict__ z2, const float* __restrict__ stats2,
    const float* __restrict__ g2, const float* __restrict__ beta2,
    const float* __restrict__ W3, const float* __restrict__ b3,
    float* __restrict__ out) {
  int wave = threadIdx.x >> 6;
  int lane = threadIdx.x & 63;
  int row = blockIdx.x * 4 + wave;
  const float* zr = z2 + (size_t)row * R_;
  float acc = 0.f;
#pragma unroll
  for (int i = 0; i < R_ / 64; ++i) {
    int j = lane + i * 64;
    float mean = stats2[j] * (1.f / B_);
    float var = stats2[R_ + j] * (1.f / B_) - mean * mean;
    float a2 = g2[j] * rsqrtf(var + EPS_);
    float c2 = beta2[j] - mean * a2;
    float h = fmaxf(zr[j] * a2 + c2, 0.f);
    acc += h * W3[j];
  }
  for (int off = 32; off > 0; off >>= 1) acc += __shfl_down(acc, off, 64);
  if (lane == 0) out[row] = acc + b3[0];
}

extern "C" void kernel_launch(void* const* d_in, const int* in_sizes, int n_in,
                              void* d_out, int out_size, void* d_ws, size_t ws_size,
                              hipStream_t stream) {
  const float* sv      = (const float*)d_in[0];
  const int*   qa_ids  = (const int*)d_in[1];
  const int*   qa_lens = (const int*)d_in[2];
  const float* emb     = (const float*)d_in[3];
  const float* W1      = (const float*)d_in[4];
  const float* b1      = (const float*)d_in[5];
  const float* g1      = (const float*)d_in[6];
  const float* beta1   = (const float*)d_in[7];
  const float* W2      = (const float*)d_in[8];
  const float* b2      = (const float*)d_in[9];
  const float* g2      = (const float*)d_in[10];
  const float* beta2   = (const float*)d_in[11];
  const float* W3      = (const float*)d_in[12];
  const float* b3      = (const float*)d_in[13];
  float* out = (float*)d_out;

  char* p = (char*)d_ws;
  short* qas    = (short*)p; p += (size_t)B_ * K1P_ * 2;        // bf16 [4096][1248]
  short* W1t    = (short*)p; p += (size_t)N1_ * K1P_ * 2;       // bf16 [1024][1248]
  short* h1     = (short*)p; p += (size_t)B_ * N1_ * 2;         // bf16 [4096][1024]
  short* W2pt   = (short*)p; p += (size_t)R_ * N1_ * 2;         // bf16 [512][1024]
  float* bias2p = (float*)p; p += R_ * 4;
  float* stats1 = (float*)p; p += 2 * N1_ * 4;
  float* stats2 = (float*)p; p += 2 * R_ * 4;
  float* part1  = (float*)p; p += (size_t)32 * 2 * N1_ * 4;     // [32 row-tiles][2048]
  float* part2  = (float*)p; p += (size_t)64 * 2 * R_ * 4;      // [64 row-tiles][1024]
  float* z2     = (float*)p;                                    // f32 [4096][512]

  // prep: blocks [0,B_) = pool+concat; blocks [B_, B_+1248) = W1 transpose/convert
  prep_kernel<<<B_ + (N1_ / 32) * (K1P_ / 32), 256, 0, stream>>>(
      sv, qa_ids, qa_lens, emb, W1, qas, W1t);
  // GEMM1: [4096,1248] @ [1248,1024] -> h1 bf16, +b1, ReLU; partial stats per row-tile
  mfma_gemm<128, 64, 2, 2, true, short>
      <<<dim3(N1_ / 64, B_ / 128), 256, 0, stream>>>(qas, W1t, b1, h1, part1, K1P_, N1_);
  reduce_stats<<<(2 * N1_ + 255) / 256, 256, 0, stream>>>(part1, stats1, 2 * N1_, B_ / 128);
  fold_kernel<<<R_, 256, 0, stream>>>(W2, b2, g1, beta1, stats1, W2pt, bias2p);
  // GEMM2: [4096,1024] @ [1024,512] -> z2 f32, +bias2p; partial stats per row-tile
  mfma_gemm<64, 64, 2, 2, false, float>
      <<<dim3(R_ / 64, B_ / 64), 256, 0, stream>>>(h1, W2pt, bias2p, z2, part2, N1_, R_);
  reduce_stats<<<(2 * R_ + 255) / 256, 256, 0, stream>>>(part2, stats2, 2 * R_, B_ / 64);
  final_kernel<<<B_ / 4, 256, 0, stream>>>(z2, stats2, g2, beta2, W3, b3, out);
}

// Round 7
// 110.792 us; speedup vs baseline: 3.2856x; 1.2669x over previous
//
#include <hip/hip_runtime.h>
#include <hip/hip_bf16.h>

#define B_ 4096
#define L_ 128
#define D_ 100
#define S_ 1024
#define R_ 512
#define K1P_ 1280   // 2*D + S padded to multiple of 64
#define N1_ 1024    // 2*R
#define EPS_ 1e-5f

typedef short bf16x8 __attribute__((ext_vector_type(8)));
typedef short short4v __attribute__((ext_vector_type(4)));
typedef float f32x4 __attribute__((ext_vector_type(4)));

static __device__ __forceinline__ short f2bf(float x) {
  union { float f; unsigned u; } c; c.f = x;
  unsigned r = (c.u + 0x7fffu + ((c.u >> 16) & 1u)) >> 16;  // RNE
  return (short)r;
}
static __device__ __forceinline__ float bf2f(short x) {
  union { unsigned u; float f; } c; c.u = ((unsigned)(unsigned short)x) << 16;
  return c.f;
}

// ---------------- prep: pool (blocks < B_) + W1 transpose/convert (blocks >= B_) -------
__global__ __launch_bounds__(256) void prep_kernel(
    const float* __restrict__ sv, const int* __restrict__ qa_ids,
    const int* __restrict__ qa_lens, const float* __restrict__ emb,
    const float* __restrict__ W1, short* __restrict__ qas,
    short* __restrict__ W1t) {
  int t = threadIdx.x;
  if (blockIdx.x < B_) {
    int b = blockIdx.x;
    __shared__ int ids[L_ * 2];
    __shared__ __align__(16) float partial[4][D_];
    int len = qa_lens[b];
    ids[t] = qa_ids[(size_t)b * (L_ * 2) + t];
    __syncthreads();
    int w = t >> 6, l = t & 63;
    if (l < 25) {  // 25 lanes x float4 = one 400B emb row per wave-instruction
      float4 a = {0.f, 0.f, 0.f, 0.f};
      for (int r = w; r < 2 * len; r += 4) {
        const float* row = emb + (size_t)ids[r] * D_;
        float4 v = *reinterpret_cast<const float4*>(row + l * 4);
        a.x += v.x; a.y += v.y; a.z += v.z; a.w += v.w;
      }
      *reinterpret_cast<float4*>(&partial[w][l * 4]) = a;
    }
    __syncthreads();
    short* qrow = qas + (size_t)b * K1P_;
    if (t < 200) {
      int k = t / 100, d = t - k * 100;
      float s = partial[k][d] + partial[k + 2][d];  // waves k, k+2 hold parity k
      qrow[t] = f2bf(s / (float)(len > 0 ? len : 1));
    }
    {  // statement copy: 256 threads x float4 -> 4x bf16
      float4 v = *reinterpret_cast<const float4*>(sv + (size_t)b * S_ + t * 4);
      short4v o;
      o[0] = f2bf(v.x); o[1] = f2bf(v.y); o[2] = f2bf(v.z); o[3] = f2bf(v.w);
      *(short4v*)&qrow[200 + t * 4] = o;
    }
    if (t < K1P_ - 1224) qrow[1224 + t] = 0;  // zero K-pad (1224..1279)
  } else {
    // W1 [1224][1024] f32 -> W1t [1024][1280] bf16 (transposed, zero-padded)
    __shared__ float tile[32][33];
    int bx = blockIdx.x - B_;
    int n0 = (bx & 31) * 32, k0 = (bx >> 5) * 32;   // bx>>5 in [0,40)
#pragma unroll
    for (int p = 0; p < 4; ++p) {
      int kk = (t >> 5) + p * 8, nn = t & 31;
      int k = k0 + kk;
      tile[kk][nn] = (k < 1224) ? W1[(size_t)k * N1_ + n0 + nn] : 0.f;
    }
    __syncthreads();
#pragma unroll
    for (int p = 0; p < 4; ++p) {
      int nn = (t >> 5) + p * 8, kk = t & 31;
      W1t[(size_t)(n0 + nn) * K1P_ + k0 + kk] = f2bf(tile[kk][nn]);
    }
  }
}

// ---------------- async stage: ROWS x 64 bf16 tile -> LDS via global_load_lds ----------
// LDS linear (HW: wave base + lane*16). Swizzle (involution, 3-bit XOR) applied to the
// GLOBAL source chunk so LDS slot c of row r holds global chunk c ^ (r&7).
template <int ROWS>
static __device__ __forceinline__ void stage_tile64(
    const short* __restrict__ gp, int stride, int k0, short* lds, int t) {
#pragma unroll
  for (int p = 0; p < ROWS / 32; ++p) {   // ROWS*8 chunks / 256 threads
    int off16 = p * 256 + t;              // 16B-chunk index within tile
    int r = off16 >> 3;
    int c = off16 & 7;
    int kc = c ^ (r & 7);
    const short* g = gp + (size_t)r * stride + k0 + kc * 8;
    __builtin_amdgcn_global_load_lds(
        (const __attribute__((address_space(1))) void*)g,
        (__attribute__((address_space(3))) void*)(lds + (size_t)off16 * 8),
        16, 0, 0);
  }
}

// ---------------- MFMA GEMM (BK=64, 2-phase async dbuf) + fused column partial-stats ---
// bias[col] = sum_{i<NBIAS} biasp[i*N + col]
template <int BM, int BN, int WM, int WN, bool RELU, int NBIAS>
__global__ __launch_bounds__(256) void mfma_gemm(
    const short* __restrict__ A, const short* __restrict__ Bt,
    const float* __restrict__ biasp, short* __restrict__ C,
    float* __restrict__ part, int K, int N) {
  constexpr int FM = BM / WM / 16;
  constexpr int FN = BN / WN / 16;
  __shared__ short As[2][BM * 64];
  __shared__ short Bs[2][BN * 64];
  __shared__ float sred[WM][WN][FN][16];
  __shared__ float qred[WM][WN][FN][16];
  const int t = threadIdx.x;
  const int l = t & 63, w = t >> 6;
  const int wr = w / WN, wc = w % WN;
  const int row0 = blockIdx.y * BM, col0 = blockIdx.x * BN;
  const short* Ab = A + (size_t)row0 * K;
  const short* Bb = Bt + (size_t)col0 * K;
  f32x4 acc[FM][FN] = {};
  const int lrow = l & 15, lkc = l >> 4;
  const int nt = K / 64;
  stage_tile64<BM>(Ab, K, 0, As[0], t);
  stage_tile64<BN>(Bb, K, 0, Bs[0], t);
  __syncthreads();  // vmcnt(0)+lgkm drain + barrier
  for (int ts = 0; ts < nt; ++ts) {
    const int cur = ts & 1;
    if (ts + 1 < nt) {  // prefetch next K-tile into the other buffer
      stage_tile64<BM>(Ab, K, (ts + 1) * 64, As[cur ^ 1], t);
      stage_tile64<BN>(Bb, K, (ts + 1) * 64, Bs[cur ^ 1], t);
    }
    bf16x8 af[2][FM], bfr[2][FN];
#pragma unroll
    for (int ks = 0; ks < 2; ++ks) {
#pragma unroll
      for (int m = 0; m < FM; ++m) {
        int r = wr * (BM / WM) + m * 16 + lrow;
        int ch = (ks * 4 + lkc) ^ (r & 7);
        af[ks][m] = *(const bf16x8*)&As[cur][r * 64 + ch * 8];
      }
#pragma unroll
      for (int n = 0; n < FN; ++n) {
        int r = wc * (BN / WN) + n * 16 + lrow;
        int ch = (ks * 4 + lkc) ^ (r & 7);
        bfr[ks][n] = *(const bf16x8*)&Bs[cur][r * 64 + ch * 8];
      }
    }
#pragma unroll
    for (int ks = 0; ks < 2; ++ks)
#pragma unroll
      for (int m = 0; m < FM; ++m)
#pragma unroll
        for (int n = 0; n < FN; ++n)
          acc[m][n] = __builtin_amdgcn_mfma_f32_16x16x32_bf16(
              af[ks][m], bfr[ks][n], acc[m][n], 0, 0, 0);
    __syncthreads();  // drains prefetch + protects buffer reuse
  }
  // epilogue: C/D layout col = lane&15, row = (lane>>4)*4 + j; fused stats on STORED vals
  float ss[FN], qq[FN];
#pragma unroll
  for (int n = 0; n < FN; ++n) { ss[n] = 0.f; qq[n] = 0.f; }
#pragma unroll
  for (int m = 0; m < FM; ++m) {
#pragma unroll
    for (int n = 0; n < FN; ++n) {
      int col = col0 + wc * (BN / WN) + n * 16 + lrow;
      float bv = 0.f;
#pragma unroll
      for (int i = 0; i < NBIAS; ++i) bv += biasp[(size_t)i * N + col];
#pragma unroll
      for (int j = 0; j < 4; ++j) {
        int row = row0 + wr * (BM / WM) + m * 16 + (l >> 4) * 4 + j;
        float v = acc[m][n][j] + bv;
        if (RELU) v = fmaxf(v, 0.f);
        short vb = f2bf(v);
        C[(size_t)row * N + col] = vb;
        float f = bf2f(vb);
        ss[n] += f;
        qq[n] += f * f;
      }
    }
  }
#pragma unroll
  for (int n = 0; n < FN; ++n) {
    ss[n] += __shfl_xor(ss[n], 16);
    ss[n] += __shfl_xor(ss[n], 32);
    qq[n] += __shfl_xor(qq[n], 16);
    qq[n] += __shfl_xor(qq[n], 32);
  }
  if (l < 16) {
#pragma unroll
    for (int n = 0; n < FN; ++n) {
      sred[wr][wc][n][l] = ss[n];
      qred[wr][wc][n][l] = qq[n];
    }
  }
  __syncthreads();
  if (t < WN * FN * 16) {
    int c16 = t & 15, n = (t >> 4) % FN, wcc = t / (16 * FN);
    float s = 0.f, q = 0.f;
#pragma unroll
    for (int r = 0; r < WM; ++r) { s += sred[r][wcc][n][c16]; q += qred[r][wcc][n][c16]; }
    int col = col0 + wcc * (BN / WN) + n * 16 + c16;
    part[(size_t)blockIdx.y * 2 * N + col] = s;
    part[(size_t)blockIdx.y * 2 * N + N + col] = q;
  }
}

// ---------------- fold_tile: reduce stats1 + BN1-fold + transpose W2 (coalesced) -------
// grid (16 kt, 8 jt). Writes W2pt[j][k] = a1[k]*W2[k][j] (bf16) and
// pbias[kt][j] = sum_{k in tile} c1[k]*W2[k][j]  (+ b2[j] folded into kt==0).
__global__ __launch_bounds__(256) void fold_tile(
    const float* __restrict__ part1, const float* __restrict__ W2,
    const float* __restrict__ b2, const float* __restrict__ g1,
    const float* __restrict__ beta1, short* __restrict__ W2pt,
    float* __restrict__ pbias) {
  int kt = blockIdx.x, jt = blockIdx.y;
  int t = threadIdx.x;
  int k0 = kt * 64, j0 = jt * 64;
  __shared__ float a1s[64], c1s[64];
  __shared__ float tT[64][65];     // [jj][kk] scaled, padded
  __shared__ float bred[16][64];   // [k-group][jj] bias partials
  if (t < 64) {  // phase A: reduce part1 over 32 row-tiles -> a1,c1 for this k-slice
    float s = 0.f, q = 0.f;
    for (int b = 0; b < 32; ++b) {
      s += part1[(size_t)b * 2048 + k0 + t];
      q += part1[(size_t)b * 2048 + 1024 + k0 + t];
    }
    float mean = s * (1.f / B_);
    float var = q * (1.f / B_) - mean * mean;
    float a = g1[k0 + t] * rsqrtf(var + EPS_);
    a1s[t] = a;
    c1s[t] = beta1[k0 + t] - mean * a;
  }
  __syncthreads();
  int g = t >> 4, j4 = t & 15;  // g: k-group 0..15, j4: j-quad 0..15
  float pb0 = 0.f, pb1 = 0.f, pb2 = 0.f, pb3 = 0.f;
#pragma unroll
  for (int p = 0; p < 4; ++p) {  // phase B: coalesced W2 rows -> scaled transpose in LDS
    int kk = g + p * 16;
    float4 wv = *(const float4*)&W2[(size_t)(k0 + kk) * R_ + j0 + j4 * 4];
    float a = a1s[kk], cc = c1s[kk];
    tT[j4 * 4 + 0][kk] = a * wv.x;
    tT[j4 * 4 + 1][kk] = a * wv.y;
    tT[j4 * 4 + 2][kk] = a * wv.z;
    tT[j4 * 4 + 3][kk] = a * wv.w;
    pb0 += cc * wv.x; pb1 += cc * wv.y; pb2 += cc * wv.z; pb3 += cc * wv.w;
  }
  bred[g][j4 * 4 + 0] = pb0;
  bred[g][j4 * 4 + 1] = pb1;
  bred[g][j4 * 4 + 2] = pb2;
  bred[g][j4 * 4 + 3] = pb3;
  __syncthreads();
#pragma unroll
  for (int p = 0; p < 4; ++p) {  // write W2pt rows (coalesced in k)
    int jj = g + p * 16;
    short4v o;
    o[0] = f2bf(tT[jj][j4 * 4 + 0]);
    o[1] = f2bf(tT[jj][j4 * 4 + 1]);
    o[2] = f2bf(tT[jj][j4 * 4 + 2]);
    o[3] = f2bf(tT[jj][j4 * 4 + 3]);
    *(short4v*)&W2pt[(size_t)(j0 + jj) * N1_ + k0 + j4 * 4] = o;
  }
  if (t < 64) {
    float pbv = 0.f;
#pragma unroll
    for (int gg = 0; gg < 16; ++gg) pbv += bred[gg][t];
    if (kt == 0) pbv += b2[j0 + t];
    pbias[(size_t)kt * R_ + j0 + t] = pbv;
  }
}

// ---------------- reduce part2 -> a2/c2 directly ---------------------------------------
__global__ __launch_bounds__(256) void reduce_bn2(
    const float* __restrict__ part2, const float* __restrict__ g2,
    const float* __restrict__ beta2, float* __restrict__ a2c2) {
  int j = blockIdx.x * 256 + threadIdx.x;
  if (j >= R_) return;
  float s = 0.f, q = 0.f;
  for (int b = 0; b < 64; ++b) {
    s += part2[(size_t)b * 1024 + j];
    q += part2[(size_t)b * 1024 + 512 + j];
  }
  float mean = s * (1.f / B_);
  float var = q * (1.f / B_) - mean * mean;
  float a = g2[j] * rsqrtf(var + EPS_);
  a2c2[j] = a;
  a2c2[R_ + j] = beta2[j] - mean * a;
}

// ---------------- final: logits = relu(a2*z2+c2) @ W3 + b3 -----------------------------
__global__ __launch_bounds__(256) void final_kernel(
    const short* __restrict__ z2, const float* __restrict__ a2c2,
    const float* __restrict__ W3, const float* __restrict__ b3,
    float* __restrict__ out) {
  int wave = threadIdx.x >> 6;
  int lane = threadIdx.x & 63;
  int row = blockIdx.x * 4 + wave;
  const short* zr = z2 + (size_t)row * R_;
  int j0 = lane * 8;
  bf16x8 zv = *(const bf16x8*)&zr[j0];
  float acc = 0.f;
#pragma unroll
  for (int i = 0; i < 8; ++i) {
    float h = fmaxf(bf2f(zv[i]) * a2c2[j0 + i] + a2c2[R_ + j0 + i], 0.f);
    acc += h * W3[j0 + i];
  }
  for (int off = 32; off > 0; off >>= 1) acc += __shfl_down(acc, off, 64);
  if (lane == 0) out[row] = acc + b3[0];
}

extern "C" void kernel_launch(void* const* d_in, const int* in_sizes, int n_in,
                              void* d_out, int out_size, void* d_ws, size_t ws_size,
                              hipStream_t stream) {
  const float* sv      = (const float*)d_in[0];
  const int*   qa_ids  = (const int*)d_in[1];
  const int*   qa_lens = (const int*)d_in[2];
  const float* emb     = (const float*)d_in[3];
  const float* W1      = (const float*)d_in[4];
  const float* b1      = (const float*)d_in[5];
  const float* g1      = (const float*)d_in[6];
  const float* beta1   = (const float*)d_in[7];
  const float* W2      = (const float*)d_in[8];
  const float* b2      = (const float*)d_in[9];
  const float* g2      = (const float*)d_in[10];
  const float* beta2   = (const float*)d_in[11];
  const float* W3      = (const float*)d_in[12];
  const float* b3      = (const float*)d_in[13];
  float* out = (float*)d_out;

  char* p = (char*)d_ws;
  short* qas    = (short*)p; p += (size_t)B_ * K1P_ * 2;        // bf16 [4096][1280]
  short* W1t    = (short*)p; p += (size_t)N1_ * K1P_ * 2;       // bf16 [1024][1280]
  short* h1     = (short*)p; p += (size_t)B_ * N1_ * 2;         // bf16 [4096][1024]
  short* W2pt   = (short*)p; p += (size_t)R_ * N1_ * 2;         // bf16 [512][1024]
  short* z2     = (short*)p; p += (size_t)B_ * R_ * 2;          // bf16 [4096][512]
  float* pbias  = (float*)p; p += (size_t)16 * R_ * 4;          // [16][512]
  float* a2c2   = (float*)p; p += 2 * R_ * 4;
  float* part1  = (float*)p; p += (size_t)32 * 2 * N1_ * 4;     // [32 row-tiles][2048]
  float* part2  = (float*)p;                                    // [64 row-tiles][1024]

  // prep: blocks [0,B_) = pool+concat; blocks [B_, B_+1280) = W1 transpose/convert
  prep_kernel<<<B_ + 32 * (K1P_ / 32), 256, 0, stream>>>(
      sv, qa_ids, qa_lens, emb, W1, qas, W1t);
  // GEMM1: [4096,1280] @ [1280,1024] -> h1 bf16, +b1, ReLU; partial stats per row-tile
  mfma_gemm<128, 64, 2, 2, true, 1>
      <<<dim3(N1_ / 64, B_ / 128), 256, 0, stream>>>(qas, W1t, b1, h1, part1, K1P_, N1_);
  // fold: stats1 reduce + BN1-fold into W2 (transposed bf16) + bias partials
  fold_tile<<<dim3(16, 8), 256, 0, stream>>>(part1, W2, b2, g1, beta1, W2pt, pbias);
  // GEMM2: [4096,1024] @ [1024,512] -> z2 bf16, bias = sum(pbias); partial stats
  mfma_gemm<64, 64, 2, 2, false, 16>
      <<<dim3(R_ / 64, B_ / 64), 256, 0, stream>>>(h1, W2pt, pbias, z2, part2, N1_, R_);
  reduce_bn2<<<2, 256, 0, stream>>>(part2, g2, beta2, a2c2);
  final_kernel<<<B_ / 4, 256, 0, stream>>>(z2, a2c2, W3, b3, out);
}

// Round 8
// 100.846 us; speedup vs baseline: 3.6097x; 1.0986x over previous
//
#include <hip/hip_runtime.h>
#include <hip/hip_bf16.h>

#define B_ 4096
#define L_ 128
#define D_ 100
#define S_ 1024
#define R_ 512
#define K1P_ 1280   // 2*D + S padded to multiple of 64
#define N1_ 1024    // 2*R
#define EPS_ 1e-5f
#define NW1BLK_ (32 * (K1P_ / 32))   // 1280 W1-convert blocks

typedef short bf16x8 __attribute__((ext_vector_type(8)));
typedef short short4v __attribute__((ext_vector_type(4)));
typedef float f32x4 __attribute__((ext_vector_type(4)));

static __device__ __forceinline__ short f2bf(float x) {
  union { float f; unsigned u; } c; c.f = x;
  unsigned r = (c.u + 0x7fffu + ((c.u >> 16) & 1u)) >> 16;  // RNE
  return (short)r;
}
static __device__ __forceinline__ float bf2f(short x) {
  union { unsigned u; float f; } c; c.u = ((unsigned)(unsigned short)x) << 16;
  return c.f;
}

// ---------------- prep: W1 transpose/convert (blocks < NW1BLK_) + pool (rest) ----------
__global__ __launch_bounds__(256) void prep_kernel(
    const float* __restrict__ sv, const int* __restrict__ qa_ids,
    const int* __restrict__ qa_lens, const float* __restrict__ emb,
    const float* __restrict__ W1, short* __restrict__ qas,
    short* __restrict__ W1t) {
  int t = threadIdx.x;
  if (blockIdx.x < NW1BLK_) {
    // W1 [1224][1024] f32 -> W1t [1024][1280] bf16 (transposed, zero-padded)
    __shared__ float tile[32][33];
    int bx = blockIdx.x;
    int n0 = (bx & 31) * 32, k0 = (bx >> 5) * 32;   // bx>>5 in [0,40)
#pragma unroll
    for (int p = 0; p < 4; ++p) {
      int kk = (t >> 5) + p * 8, nn = t & 31;
      int k = k0 + kk;
      tile[kk][nn] = (k < 1224) ? W1[(size_t)k * N1_ + n0 + nn] : 0.f;
    }
    __syncthreads();
#pragma unroll
    for (int p = 0; p < 4; ++p) {
      int nn = (t >> 5) + p * 8, kk = t & 31;
      W1t[(size_t)(n0 + nn) * K1P_ + k0 + kk] = f2bf(tile[kk][nn]);
    }
  } else {
    int b = blockIdx.x - NW1BLK_;
    __shared__ int ids[L_ * 2];
    __shared__ __align__(16) float partial[4][2][D_];  // [wave][row-slot][d]
    int len = qa_lens[b];
    ids[t] = qa_ids[(size_t)b * (L_ * 2) + t];
    __syncthreads();
    int w = t >> 6, l = t & 63;
    int rs = l >> 5;   // wave's row-slot (0/1); row parity == rs
    int li = l & 31;   // lane within row
    if (li < 25) {     // 25 lanes x float4 = one 400B emb row per slot
      float4 a0 = {0.f, 0.f, 0.f, 0.f}, a1 = {0.f, 0.f, 0.f, 0.f};
      int n2 = 2 * len;
      int r = 2 * w + rs;               // residue 2w+rs (mod 8)
      for (; r + 8 < n2; r += 16) {     // 2 independent gathers in flight
        const float* row0 = emb + (size_t)ids[r] * D_;
        const float* row1 = emb + (size_t)ids[r + 8] * D_;
        float4 v0 = *reinterpret_cast<const float4*>(row0 + li * 4);
        float4 v1 = *reinterpret_cast<const float4*>(row1 + li * 4);
        a0.x += v0.x; a0.y += v0.y; a0.z += v0.z; a0.w += v0.w;
        a1.x += v1.x; a1.y += v1.y; a1.z += v1.z; a1.w += v1.w;
      }
      if (r < n2) {
        const float* row0 = emb + (size_t)ids[r] * D_;
        float4 v0 = *reinterpret_cast<const float4*>(row0 + li * 4);
        a0.x += v0.x; a0.y += v0.y; a0.z += v0.z; a0.w += v0.w;
      }
      a0.x += a1.x; a0.y += a1.y; a0.z += a1.z; a0.w += a1.w;
      *reinterpret_cast<float4*>(&partial[w][rs][li * 4]) = a0;
    }
    __syncthreads();
    short* qrow = qas + (size_t)b * K1P_;
    if (t < 200) {
      int k = t / 100, d = t - k * 100;
      float s = partial[0][k][d] + partial[1][k][d] +
                partial[2][k][d] + partial[3][k][d];
      qrow[t] = f2bf(s / (float)(len > 0 ? len : 1));
    }
    {  // statement copy: 256 threads x float4 -> 4x bf16
      float4 v = *reinterpret_cast<const float4*>(sv + (size_t)b * S_ + t * 4);
      short4v o;
      o[0] = f2bf(v.x); o[1] = f2bf(v.y); o[2] = f2bf(v.z); o[3] = f2bf(v.w);
      *(short4v*)&qrow[200 + t * 4] = o;
    }
    if (t < K1P_ - 1224) qrow[1224 + t] = 0;  // zero K-pad (1224..1279)
  }
}

// ---------------- async stage: ROWS x 64 bf16 tile -> LDS via global_load_lds ----------
// LDS linear (HW: wave base + lane*16). Swizzle (involution, 3-bit XOR) applied to the
// GLOBAL source chunk so LDS slot c of row r holds global chunk c ^ (r&7).
template <int ROWS>
static __device__ __forceinline__ void stage_tile64(
    const short* __restrict__ gp, int stride, int k0, short* lds, int t) {
#pragma unroll
  for (int p = 0; p < ROWS / 32; ++p) {   // ROWS*8 chunks / 256 threads
    int off16 = p * 256 + t;              // 16B-chunk index within tile
    int r = off16 >> 3;
    int c = off16 & 7;
    int kc = c ^ (r & 7);
    const short* g = gp + (size_t)r * stride + k0 + kc * 8;
    __builtin_amdgcn_global_load_lds(
        (const __attribute__((address_space(1))) void*)g,
        (__attribute__((address_space(3))) void*)(lds + (size_t)off16 * 8),
        16, 0, 0);
  }
}

// ---------------- MFMA GEMM (BK=64, 2-phase async dbuf) + fused column partial-stats ---
// bias[col] = sum_{i<NBIAS} biasp[i*N + col]
template <int BM, int BN, int WM, int WN, bool RELU, int NBIAS>
__global__ __launch_bounds__(256) void mfma_gemm(
    const short* __restrict__ A, const short* __restrict__ Bt,
    const float* __restrict__ biasp, short* __restrict__ C,
    float* __restrict__ part, int K, int N) {
  constexpr int FM = BM / WM / 16;
  constexpr int FN = BN / WN / 16;
  __shared__ short As[2][BM * 64];
  __shared__ short Bs[2][BN * 64];
  __shared__ float sred[WM][WN][FN][16];
  __shared__ float qred[WM][WN][FN][16];
  const int t = threadIdx.x;
  const int l = t & 63, w = t >> 6;
  const int wr = w / WN, wc = w % WN;
  const int row0 = blockIdx.y * BM, col0 = blockIdx.x * BN;
  const short* Ab = A + (size_t)row0 * K;
  const short* Bb = Bt + (size_t)col0 * K;
  f32x4 acc[FM][FN] = {};
  const int lrow = l & 15, lkc = l >> 4;
  const int nt = K / 64;
  stage_tile64<BM>(Ab, K, 0, As[0], t);
  stage_tile64<BN>(Bb, K, 0, Bs[0], t);
  __syncthreads();  // vmcnt(0)+lgkm drain + barrier
  for (int ts = 0; ts < nt; ++ts) {
    const int cur = ts & 1;
    if (ts + 1 < nt) {  // prefetch next K-tile into the other buffer
      stage_tile64<BM>(Ab, K, (ts + 1) * 64, As[cur ^ 1], t);
      stage_tile64<BN>(Bb, K, (ts + 1) * 64, Bs[cur ^ 1], t);
    }
    bf16x8 af[2][FM], bfr[2][FN];
#pragma unroll
    for (int ks = 0; ks < 2; ++ks) {
#pragma unroll
      for (int m = 0; m < FM; ++m) {
        int r = wr * (BM / WM) + m * 16 + lrow;
        int ch = (ks * 4 + lkc) ^ (r & 7);
        af[ks][m] = *(const bf16x8*)&As[cur][r * 64 + ch * 8];
      }
#pragma unroll
      for (int n = 0; n < FN; ++n) {
        int r = wc * (BN / WN) + n * 16 + lrow;
        int ch = (ks * 4 + lkc) ^ (r & 7);
        bfr[ks][n] = *(const bf16x8*)&Bs[cur][r * 64 + ch * 8];
      }
    }
#pragma unroll
    for (int ks = 0; ks < 2; ++ks)
#pragma unroll
      for (int m = 0; m < FM; ++m)
#pragma unroll
        for (int n = 0; n < FN; ++n)
          acc[m][n] = __builtin_amdgcn_mfma_f32_16x16x32_bf16(
              af[ks][m], bfr[ks][n], acc[m][n], 0, 0, 0);
    __syncthreads();  // drains prefetch + protects buffer reuse
  }
  // epilogue: C/D layout col = lane&15, row = (lane>>4)*4 + j; fused stats on STORED vals
  float ss[FN], qq[FN];
#pragma unroll
  for (int n = 0; n < FN; ++n) { ss[n] = 0.f; qq[n] = 0.f; }
#pragma unroll
  for (int m = 0; m < FM; ++m) {
#pragma unroll
    for (int n = 0; n < FN; ++n) {
      int col = col0 + wc * (BN / WN) + n * 16 + lrow;
      float bv = 0.f;
#pragma unroll
      for (int i = 0; i < NBIAS; ++i) bv += biasp[(size_t)i * N + col];
#pragma unroll
      for (int j = 0; j < 4; ++j) {
        int row = row0 + wr * (BM / WM) + m * 16 + (l >> 4) * 4 + j;
        float v = acc[m][n][j] + bv;
        if (RELU) v = fmaxf(v, 0.f);
        short vb = f2bf(v);
        C[(size_t)row * N + col] = vb;
        float f = bf2f(vb);
        ss[n] += f;
        qq[n] += f * f;
      }
    }
  }
#pragma unroll
  for (int n = 0; n < FN; ++n) {
    ss[n] += __shfl_xor(ss[n], 16);
    ss[n] += __shfl_xor(ss[n], 32);
    qq[n] += __shfl_xor(qq[n], 16);
    qq[n] += __shfl_xor(qq[n], 32);
  }
  if (l < 16) {
#pragma unroll
    for (int n = 0; n < FN; ++n) {
      sred[wr][wc][n][l] = ss[n];
      qred[wr][wc][n][l] = qq[n];
    }
  }
  __syncthreads();
  if (t < WN * FN * 16) {
    int c16 = t & 15, n = (t >> 4) % FN, wcc = t / (16 * FN);
    float s = 0.f, q = 0.f;
#pragma unroll
    for (int r = 0; r < WM; ++r) { s += sred[r][wcc][n][c16]; q += qred[r][wcc][n][c16]; }
    int col = col0 + wcc * (BN / WN) + n * 16 + c16;
    part[(size_t)blockIdx.y * 2 * N + col] = s;
    part[(size_t)blockIdx.y * 2 * N + N + col] = q;
  }
}

// ---------------- fold_tile: reduce stats1 + BN1-fold + transpose W2 (coalesced) -------
// grid (16 kt, 8 jt). Writes W2pt[j][k] = a1[k]*W2[k][j] (bf16) and
// pbias[kt][j] = sum_{k in tile} c1[k]*W2[k][j]  (+ b2[j] folded into kt==0).
__global__ __launch_bounds__(256) void fold_tile(
    const float* __restrict__ part1, const float* __restrict__ W2,
    const float* __restrict__ b2, const float* __restrict__ g1,
    const float* __restrict__ beta1, short* __restrict__ W2pt,
    float* __restrict__ pbias) {
  int kt = blockIdx.x, jt = blockIdx.y;
  int t = threadIdx.x;
  int k0 = kt * 64, j0 = jt * 64;
  __shared__ float a1s[64], c1s[64];
  __shared__ float tT[64][65];     // [jj][kk] scaled, padded
  __shared__ float bred[16][64];   // [k-group][jj] bias partials
  if (t < 64) {  // phase A: reduce part1 over 32 row-tiles -> a1,c1 for this k-slice
    float s = 0.f, q = 0.f;
    for (int b = 0; b < 32; ++b) {
      s += part1[(size_t)b * 2048 + k0 + t];
      q += part1[(size_t)b * 2048 + 1024 + k0 + t];
    }
    float mean = s * (1.f / B_);
    float var = q * (1.f / B_) - mean * mean;
    float a = g1[k0 + t] * rsqrtf(var + EPS_);
    a1s[t] = a;
    c1s[t] = beta1[k0 + t] - mean * a;
  }
  __syncthreads();
  int g = t >> 4, j4 = t & 15;  // g: k-group 0..15, j4: j-quad 0..15
  float pb0 = 0.f, pb1 = 0.f, pb2 = 0.f, pb3 = 0.f;
#pragma unroll
  for (int p = 0; p < 4; ++p) {  // phase B: coalesced W2 rows -> scaled transpose in LDS
    int kk = g + p * 16;
    float4 wv = *(const float4*)&W2[(size_t)(k0 + kk) * R_ + j0 + j4 * 4];
    float a = a1s[kk], cc = c1s[kk];
    tT[j4 * 4 + 0][kk] = a * wv.x;
    tT[j4 * 4 + 1][kk] = a * wv.y;
    tT[j4 * 4 + 2][kk] = a * wv.z;
    tT[j4 * 4 + 3][kk] = a * wv.w;
    pb0 += cc * wv.x; pb1 += cc * wv.y; pb2 += cc * wv.z; pb3 += cc * wv.w;
  }
  bred[g][j4 * 4 + 0] = pb0;
  bred[g][j4 * 4 + 1] = pb1;
  bred[g][j4 * 4 + 2] = pb2;
  bred[g][j4 * 4 + 3] = pb3;
  __syncthreads();
#pragma unroll
  for (int p = 0; p < 4; ++p) {  // write W2pt rows (coalesced in k)
    int jj = g + p * 16;
    short4v o;
    o[0] = f2bf(tT[jj][j4 * 4 + 0]);
    o[1] = f2bf(tT[jj][j4 * 4 + 1]);
    o[2] = f2bf(tT[jj][j4 * 4 + 2]);
    o[3] = f2bf(tT[jj][j4 * 4 + 3]);
    *(short4v*)&W2pt[(size_t)(j0 + jj) * N1_ + k0 + j4 * 4] = o;
  }
  if (t < 64) {
    float pbv = 0.f;
#pragma unroll
    for (int gg = 0; gg < 16; ++gg) pbv += bred[gg][t];
    if (kt == 0) pbv += b2[j0 + t];
    pbias[(size_t)kt * R_ + j0 + t] = pbv;
  }
}

// ---------------- reduce part2 -> a2/c2 directly ---------------------------------------
__global__ __launch_bounds__(256) void reduce_bn2(
    const float* __restrict__ part2, const float* __restrict__ g2,
    const float* __restrict__ beta2, float* __restrict__ a2c2) {
  int j = blockIdx.x * 256 + threadIdx.x;
  if (j >= R_) return;
  float s = 0.f, q = 0.f;
  for (int b = 0; b < 64; ++b) {
    s += part2[(size_t)b * 1024 + j];
    q += part2[(size_t)b * 1024 + 512 + j];
  }
  float mean = s * (1.f / B_);
  float var = q * (1.f / B_) - mean * mean;
  float a = g2[j] * rsqrtf(var + EPS_);
  a2c2[j] = a;
  a2c2[R_ + j] = beta2[j] - mean * a;
}

// ---------------- final: logits = relu(a2*z2+c2) @ W3 + b3 -----------------------------
__global__ __launch_bounds__(256) void final_kernel(
    const short* __restrict__ z2, const float* __restrict__ a2c2,
    const float* __restrict__ W3, const float* __restrict__ b3,
    float* __restrict__ out) {
  int wave = threadIdx.x >> 6;
  int lane = threadIdx.x & 63;
  int row = blockIdx.x * 4 + wave;
  const short* zr = z2 + (size_t)row * R_;
  int j0 = lane * 8;
  bf16x8 zv = *(const bf16x8*)&zr[j0];
  float acc = 0.f;
#pragma unroll
  for (int i = 0; i < 8; ++i) {
    float h = fmaxf(bf2f(zv[i]) * a2c2[j0 + i] + a2c2[R_ + j0 + i], 0.f);
    acc += h * W3[j0 + i];
  }
  for (int off = 32; off > 0; off >>= 1) acc += __shfl_down(acc, off, 64);
  if (lane == 0) out[row] = acc + b3[0];
}

extern "C" void kernel_launch(void* const* d_in, const int* in_sizes, int n_in,
                              void* d_out, int out_size, void* d_ws, size_t ws_size,
                              hipStream_t stream) {
  const float* sv      = (const float*)d_in[0];
  const int*   qa_ids  = (const int*)d_in[1];
  const int*   qa_lens = (const int*)d_in[2];
  const float* emb     = (const float*)d_in[3];
  const float* W1      = (const float*)d_in[4];
  const float* b1      = (const float*)d_in[5];
  const float* g1      = (const float*)d_in[6];
  const float* beta1   = (const float*)d_in[7];
  const float* W2      = (const float*)d_in[8];
  const float* b2      = (const float*)d_in[9];
  const float* g2      = (const float*)d_in[10];
  const float* beta2   = (const float*)d_in[11];
  const float* W3      = (const float*)d_in[12];
  const float* b3      = (const float*)d_in[13];
  float* out = (float*)d_out;

  char* p = (char*)d_ws;
  short* qas    = (short*)p; p += (size_t)B_ * K1P_ * 2;        // bf16 [4096][1280]
  short* W1t    = (short*)p; p += (size_t)N1_ * K1P_ * 2;       // bf16 [1024][1280]
  short* h1     = (short*)p; p += (size_t)B_ * N1_ * 2;         // bf16 [4096][1024]
  short* W2pt   = (short*)p; p += (size_t)R_ * N1_ * 2;         // bf16 [512][1024]
  short* z2     = (short*)p; p += (size_t)B_ * R_ * 2;          // bf16 [4096][512]
  float* pbias  = (float*)p; p += (size_t)16 * R_ * 4;          // [16][512]
  float* a2c2   = (float*)p; p += 2 * R_ * 4;
  float* part1  = (float*)p; p += (size_t)32 * 2 * N1_ * 4;     // [32 row-tiles][2048]
  float* part2  = (float*)p;                                    // [64 row-tiles][1024]

  // prep: blocks [0,1280) = W1 transpose/convert (run first); rest = pool+concat
  prep_kernel<<<NW1BLK_ + B_, 256, 0, stream>>>(
      sv, qa_ids, qa_lens, emb, W1, qas, W1t);
  // GEMM1: [4096,1280] @ [1280,1024] -> h1 bf16, +b1, ReLU; partial stats per row-tile
  mfma_gemm<128, 64, 2, 2, true, 1>
      <<<dim3(N1_ / 64, B_ / 128), 256, 0, stream>>>(qas, W1t, b1, h1, part1, K1P_, N1_);
  // fold: stats1 reduce + BN1-fold into W2 (transposed bf16) + bias partials
  fold_tile<<<dim3(16, 8), 256, 0, stream>>>(part1, W2, b2, g1, beta1, W2pt, pbias);
  // GEMM2: [4096,1024] @ [1024,512] -> z2 bf16, bias = sum(pbias); partial stats
  mfma_gemm<64, 64, 2, 2, false, 16>
      <<<dim3(R_ / 64, B_ / 64), 256, 0, stream>>>(h1, W2pt, pbias, z2, part2, N1_, R_);
  reduce_bn2<<<2, 256, 0, stream>>>(part2, g2, beta2, a2c2);
  final_kernel<<<B_ / 4, 256, 0, stream>>>(z2, a2c2, W3, b3, out);
}